// Round 1
// baseline (6130.393 us; speedup 1.0000x reference)
//
#include <hip/hip_runtime.h>
#include <hip/hip_bf16.h>
#include <math.h>

#define UNITS 64
#define DEPTH_EMB 12
#define DEPTH_PAR 5
#define GN_EPS 1e-5f

// ---------------- degree / normalization ----------------

__global__ void k_deg(const int* __restrict__ dst, float* __restrict__ deg, int E) {
    int e = blockIdx.x * blockDim.x + threadIdx.x;
    if (e < E) atomicAdd(&deg[dst[e]], 1.0f);
}

__global__ void k_dinv(float* __restrict__ deg, int n) {
    int i = blockIdx.x * blockDim.x + threadIdx.x;
    if (i < n) deg[i] = rsqrtf(1.0f + deg[i]);
}

__global__ void k_ne(const int* __restrict__ src, const int* __restrict__ dst,
                     const float* __restrict__ dinv, float* __restrict__ ne, int E) {
    int e = blockIdx.x * blockDim.x + threadIdx.x;
    if (e < E) ne[e] = dinv[src[e]] * dinv[dst[e]];
}

// ---------------- layer 0: h2 = x @ w0  (x is [N,1], w0 is [1,64]) ----------------

__global__ void k_l0(const float* __restrict__ x, const float* __restrict__ w0,
                     float* __restrict__ h2, int n) {
    int gid = blockIdx.x * blockDim.x + threadIdx.x;
    if (gid >= n * UNITS) return;
    int node = gid >> 6, c = gid & 63;
    h2[gid] = x[node] * w0[c];
}

// ---------------- generic 64x64 linear: wave-per-node, W column in regs ----------------
// MODE 0: out = in @ W
// MODE 1: out = relu(in + in @ W + b)
template <int MODE>
__global__ void k_linear(const float* __restrict__ in, float* __restrict__ out,
                         const float* __restrict__ W, const float* __restrict__ b, int n) {
    int lane = threadIdx.x & 63;
    int wib = threadIdx.x >> 6;
    int wpb = blockDim.x >> 6;
    int gwave = blockIdx.x * wpb + wib;
    int nwaves = gridDim.x * wpb;

    float w[UNITS];
#pragma unroll
    for (int k = 0; k < UNITS; ++k) w[k] = W[k * UNITS + lane];
    float bj = (MODE == 1) ? b[lane] : 0.0f;

    for (int node = gwave; node < n; node += nwaves) {
        float hv = in[node * UNITS + lane];
        float acc = 0.0f;
#pragma unroll
        for (int k = 0; k < UNITS; ++k) {
            float hk = __shfl(hv, k, 64);
            acc += hk * w[k];
        }
        if (MODE == 1) {
            acc += hv + bj;
            acc = fmaxf(acc, 0.0f);
        }
        out[node * UNITS + lane] = acc;
    }
}

// ---------------- edge scatter: h[dst] += h2[src] * ne  (wave per edge) ----------------

__global__ void k_scatter(const float* __restrict__ h2, float* __restrict__ hout,
                          const int* __restrict__ src, const int* __restrict__ dst,
                          const float* __restrict__ ne, int E) {
    long long gid = (long long)blockIdx.x * blockDim.x + threadIdx.x;
    int e = (int)(gid >> 6), lane = (int)(gid & 63);
    if (e >= E) return;
    int s = src[e], d = dst[e];
    float v = h2[s * UNITS + lane] * ne[e];
    atomicAdd(&hout[d * UNITS + lane], v);
}

// ---------------- combine: h = h(agg) + h2*self_norm + b ; optional stats ----------------

__global__ void k_combine(float* __restrict__ h, const float* __restrict__ h2,
                          const float* __restrict__ dinv, const float* __restrict__ b,
                          float* __restrict__ stats, int n, int do_stats) {
    int lane = threadIdx.x & 63;
    int rib = threadIdx.x >> 6;             // 0..3
    int rpg = gridDim.x * (blockDim.x >> 6);
    float bj = b[lane];
    float s1 = 0.0f, s2 = 0.0f;
    for (int node = blockIdx.x * (blockDim.x >> 6) + rib; node < n; node += rpg) {
        float di = dinv[node];
        float sn = di * di;
        int idx = node * UNITS + lane;
        float v = h[idx] + h2[idx] * sn + bj;
        h[idx] = v;
        s1 += v;
        s2 += v * v;
    }
    if (do_stats) {
        __shared__ float sd[2][4][UNITS];
        sd[0][rib][lane] = s1;
        sd[1][rib][lane] = s2;
        __syncthreads();
        if (threadIdx.x < UNITS) {
            float a1 = sd[0][0][lane] + sd[0][1][lane] + sd[0][2][lane] + sd[0][3][lane];
            float a2 = sd[1][0][lane] + sd[1][1][lane] + sd[1][2][lane] + sd[1][3][lane];
            atomicAdd(&stats[lane], a1);
            atomicAdd(&stats[UNITS + lane], a2);
        }
    }
}

// ---------------- GraphNorm finalize: per-feature affine coefficients ----------------

__global__ void k_stats_final(const float* __restrict__ stats, const float* __restrict__ gamma,
                              const float* __restrict__ beta, const float* __restrict__ alpha,
                              float* __restrict__ sAB, float inv_n) {
    int c = threadIdx.x;
    if (c >= UNITS) return;
    float m = stats[c] * inv_n;
    float ex2 = stats[UNITS + c] * inv_n;
    float a = alpha[c];
    float var = ex2 - m * m * (2.0f * a - a * a);
    float rs = rsqrtf(var + GN_EPS);
    float g = gamma[c] * rs;
    sAB[c] = g;
    sAB[UNITS + c] = beta[c] - g * a * m;
}

// ---------------- normalize + SiLU (in place) ----------------

__global__ void k_norm_silu(float* __restrict__ h, const float* __restrict__ sAB, int total) {
    int gid = blockIdx.x * blockDim.x + threadIdx.x;
    if (gid >= total) return;
    int c = gid & 63;
    float v = h[gid] * sAB[c] + sAB[UNITS + c];
    h[gid] = v / (1.0f + expf(-v));
}

// ---------------- final head: out[n] = sigmoid(dot(in[n], wl) + bl) ----------------

__global__ void k_head(const float* __restrict__ in, const float* __restrict__ wl,
                       const float* __restrict__ bl, float* __restrict__ out, int n) {
    int lane = threadIdx.x & 63;
    int wib = threadIdx.x >> 6;
    int wpb = blockDim.x >> 6;
    int gwave = blockIdx.x * wpb + wib;
    int nwaves = gridDim.x * wpb;
    float wv = wl[lane];
    float blv = bl[0];
    for (int node = gwave; node < n; node += nwaves) {
        float p = in[node * UNITS + lane] * wv;
#pragma unroll
        for (int off = 32; off > 0; off >>= 1) p += __shfl_xor(p, off, 64);
        if (lane == 0) out[node] = 1.0f / (1.0f + expf(-(p + blv)));
    }
}

// ---------------- host launch ----------------

extern "C" void kernel_launch(void* const* d_in, const int* in_sizes, int n_in,
                              void* d_out, int out_size, void* d_ws, size_t ws_size,
                              hipStream_t stream) {
    const float* x = (const float*)d_in[0];
    const int* ei = (const int*)d_in[1];
    const float* conv_w0 = (const float*)d_in[2];
    const float* conv_w = (const float*)d_in[3];
    const float* conv_b = (const float*)d_in[4];
    const float* gn_gamma = (const float*)d_in[5];
    const float* gn_beta = (const float*)d_in[6];
    const float* gn_alpha = (const float*)d_in[7];
    const float* phe_w = (const float*)d_in[8];
    const float* phe_b = (const float*)d_in[9];
    const float* phe_wl = (const float*)d_in[10];
    const float* phe_bl = (const float*)d_in[11];
    const float* heu_w = (const float*)d_in[12];
    const float* heu_b = (const float*)d_in[13];
    const float* heu_wl = (const float*)d_in[14];
    const float* heu_bl = (const float*)d_in[15];

    const int N = in_sizes[0];       // 100000
    const int E = in_sizes[1] / 2;   // 1600000
    const int NC = N * UNITS;

    const int* src = ei;
    const int* dstp = ei + E;

    float* ws = (float*)d_ws;
    float* dinv = ws;              // N
    float* ne = dinv + N;          // E
    float* h = ne + E;             // N*64
    float* h2 = h + NC;            // N*64
    float* h3 = h2 + NC;           // N*64
    float* stats = h3 + NC;        // 128
    float* sAB = stats + 128;      // 128

    float* out = (float*)d_out;

    const int B = 256;
    const int gE = (E + B - 1) / B;
    const int gN = (N + B - 1) / B;
    const int gNC = (NC + B - 1) / B;
    const long long scat_threads = (long long)E * UNITS;
    const int gScat = (int)((scat_threads + B - 1) / B);

    // degree / dinv / edge norms
    hipMemsetAsync(dinv, 0, (size_t)N * sizeof(float), stream);
    k_deg<<<gE, B, 0, stream>>>(dstp, dinv, E);
    k_dinv<<<gN, B, 0, stream>>>(dinv, N);
    k_ne<<<gE, B, 0, stream>>>(src, dstp, dinv, ne, E);

    // GCN embedding layers
    for (int i = 0; i < DEPTH_EMB; ++i) {
        if (i == 0) {
            k_l0<<<gNC, B, 0, stream>>>(x, conv_w0, h2, N);
        } else {
            k_linear<0><<<2048, B, 0, stream>>>(h, h2, conv_w + (size_t)(i - 1) * UNITS * UNITS,
                                                nullptr, N);
        }
        hipMemsetAsync(h, 0, (size_t)NC * sizeof(float), stream);
        k_scatter<<<gScat, B, 0, stream>>>(h2, h, src, dstp, ne, E);
        int do_stats = (i < DEPTH_EMB - 1) ? 1 : 0;
        if (do_stats) hipMemsetAsync(stats, 0, 128 * sizeof(float), stream);
        k_combine<<<512, B, 0, stream>>>(h, h2, dinv, conv_b + (size_t)i * UNITS, stats, N, do_stats);
        if (do_stats) {
            k_stats_final<<<1, 64, 0, stream>>>(stats, gn_gamma + (size_t)i * UNITS,
                                                gn_beta + (size_t)i * UNITS,
                                                gn_alpha + (size_t)i * UNITS, sAB, 1.0f / (float)N);
            k_norm_silu<<<gNC, B, 0, stream>>>(h, sAB, NC);
        }
    }

    // ParNet heads (h preserved; ping-pong h2/h3)
    for (int head = 0; head < 2; ++head) {
        const float* wsrc = head == 0 ? phe_w : heu_w;
        const float* bsrc = head == 0 ? phe_b : heu_b;
        const float* wl = head == 0 ? phe_wl : heu_wl;
        const float* bl = head == 0 ? phe_bl : heu_bl;
        float* o = out + (size_t)head * N;

        const float* cur = h;
        float* nxt = h2;
        for (int l = 0; l < DEPTH_PAR - 1; ++l) {
            k_linear<1><<<2048, B, 0, stream>>>(cur, nxt, wsrc + (size_t)l * UNITS * UNITS,
                                                bsrc + (size_t)l * UNITS, N);
            cur = nxt;
            nxt = (nxt == h2) ? h3 : h2;
        }
        k_head<<<2048, B, 0, stream>>>(cur, wl, bl, o, N);
    }
}

// Round 2
// 2160.129 us; speedup vs baseline: 2.8380x; 2.8380x over previous
//
#include <hip/hip_runtime.h>
#include <hip/hip_bf16.h>
#include <math.h>

#define UNITS 64
#define DEPTH_EMB 12
#define DEPTH_PAR 5
#define GN_EPS 1e-5f

// ---------------- CSR build ----------------

__global__ void k_deg(const int* __restrict__ dst, int* __restrict__ cnt, int E) {
    int e = blockIdx.x * blockDim.x + threadIdx.x;
    if (e < E) atomicAdd(&cnt[dst[e]], 1);
}

__global__ void k_dinv(const int* __restrict__ cnt, float* __restrict__ dinv, int n) {
    int i = blockIdx.x * blockDim.x + threadIdx.x;
    if (i < n) dinv[i] = rsqrtf(1.0f + (float)cnt[i]);
}

// single-block scan: rowptr[0]=0, rowptr[i+1] = sum cnt[0..i]
__global__ void k_scan(const int* __restrict__ cnt, int* __restrict__ rowptr, int n) {
    __shared__ int buf[1024];
    __shared__ int carry_s;
    int tid = threadIdx.x;
    if (tid == 0) carry_s = 0;
    __syncthreads();
    for (int base = 0; base < n; base += 1024) {
        int i = base + tid;
        int v = (i < n) ? cnt[i] : 0;
        buf[tid] = v;
        __syncthreads();
#pragma unroll
        for (int off = 1; off < 1024; off <<= 1) {
            int t = (tid >= off) ? buf[tid - off] : 0;
            __syncthreads();
            buf[tid] += t;
            __syncthreads();
        }
        if (i < n) rowptr[i + 1] = carry_s + buf[tid];
        __syncthreads();
        if (tid == 1023) carry_s += buf[1023];
        __syncthreads();
    }
    if (tid == 0) rowptr[0] = 0;
}

__global__ void k_fill(const int* __restrict__ src, const int* __restrict__ dst,
                       const float* __restrict__ dinv, const int* __restrict__ rowptr,
                       int* __restrict__ fill, int* __restrict__ srcs,
                       float* __restrict__ nes, int E) {
    int e = blockIdx.x * blockDim.x + threadIdx.x;
    if (e >= E) return;
    int s = src[e], d = dst[e];
    int p = rowptr[d] + atomicAdd(&fill[d], 1);
    srcs[p] = s;
    nes[p] = dinv[s] * dinv[d];
}

// ---------------- layer 0: h2 = x @ w0 ----------------

__global__ void k_l0(const float* __restrict__ x, const float* __restrict__ w0,
                     float* __restrict__ h2, int n) {
    int gid = blockIdx.x * blockDim.x + threadIdx.x;
    if (gid >= n * UNITS) return;
    int node = gid >> 6, c = gid & 63;
    h2[gid] = x[node] * w0[c];
}

// ---------------- 64x64 linear, scalar-broadcast row ----------------
// MODE 0: out = in @ W
// MODE 1: out = relu(in + in @ W + b)
template <int MODE>
__global__ void k_linear(const float* __restrict__ in, float* __restrict__ out,
                         const float* __restrict__ W, const float* __restrict__ b, int n) {
    int lane = threadIdx.x & 63;
    int wib = threadIdx.x >> 6;
    int wpb = blockDim.x >> 6;
    int gwave = blockIdx.x * wpb + wib;
    int nwaves = gridDim.x * wpb;

    float w[UNITS];
#pragma unroll
    for (int k = 0; k < UNITS; ++k) w[k] = W[k * UNITS + lane];
    float bj = (MODE == 1) ? b[lane] : 0.0f;

    for (int nd = gwave; nd < n; nd += nwaves) {
        int node = __builtin_amdgcn_readfirstlane(nd);
        const float* __restrict__ row = in + (size_t)node * UNITS;
        float acc = 0.0f;
#pragma unroll
        for (int k = 0; k < UNITS; ++k) acc = fmaf(row[k], w[k], acc);
        if (MODE == 1) {
            acc += row[lane] + bj;
            acc = fmaxf(acc, 0.0f);
        }
        out[(size_t)node * UNITS + lane] = acc;
    }
}

// ---------------- gather + combine + stats (replaces scatter+combine) ----------------

template <int DO_STATS>
__global__ void k_gather(const float* __restrict__ h2, float* __restrict__ h,
                         const int* __restrict__ rowptr, const int* __restrict__ srcs,
                         const float* __restrict__ nes, const float* __restrict__ dinv,
                         const float* __restrict__ b, float* __restrict__ stats, int n) {
    int lane = threadIdx.x & 63;
    int wib = threadIdx.x >> 6;
    int wpb = blockDim.x >> 6;
    int gwave = blockIdx.x * wpb + wib;
    int nwaves = gridDim.x * wpb;
    float bj = b[lane];
    float s1 = 0.0f, s2 = 0.0f;

    for (int nd = gwave; nd < n; nd += nwaves) {
        int node = __builtin_amdgcn_readfirstlane(nd);
        int beg = rowptr[node], end = rowptr[node + 1];
        float di = dinv[node];
        float acc = fmaf(h2[(size_t)node * UNITS + lane], di * di, bj);
        float acc1 = 0.0f;
        int j = beg;
        for (; j + 4 <= end; j += 4) {
            int i0 = srcs[j + 0], i1 = srcs[j + 1], i2 = srcs[j + 2], i3 = srcs[j + 3];
            float w0 = nes[j + 0], w1 = nes[j + 1], w2 = nes[j + 2], w3 = nes[j + 3];
            float v0 = h2[(size_t)i0 * UNITS + lane];
            float v1 = h2[(size_t)i1 * UNITS + lane];
            float v2 = h2[(size_t)i2 * UNITS + lane];
            float v3 = h2[(size_t)i3 * UNITS + lane];
            acc = fmaf(w0, v0, acc);
            acc1 = fmaf(w1, v1, acc1);
            acc = fmaf(w2, v2, acc);
            acc1 = fmaf(w3, v3, acc1);
        }
        for (; j < end; ++j) acc = fmaf(nes[j], h2[(size_t)srcs[j] * UNITS + lane], acc);
        acc += acc1;
        h[(size_t)node * UNITS + lane] = acc;
        if (DO_STATS) {
            s1 += acc;
            s2 = fmaf(acc, acc, s2);
        }
    }

    if (DO_STATS) {
        __shared__ float sd[2][4][UNITS];
        sd[0][wib][lane] = s1;
        sd[1][wib][lane] = s2;
        __syncthreads();
        if (threadIdx.x < UNITS) {
            float a1 = 0.0f, a2 = 0.0f;
            for (int r = 0; r < wpb; ++r) {
                a1 += sd[0][r][lane];
                a2 += sd[1][r][lane];
            }
            atomicAdd(&stats[lane], a1);
            atomicAdd(&stats[UNITS + lane], a2);
        }
    }
}

// ---------------- GraphNorm finalize ----------------

__global__ void k_stats_final(const float* __restrict__ stats, const float* __restrict__ gamma,
                              const float* __restrict__ beta, const float* __restrict__ alpha,
                              float* __restrict__ sAB, float inv_n) {
    int c = threadIdx.x;
    if (c >= UNITS) return;
    float m = stats[c] * inv_n;
    float ex2 = stats[UNITS + c] * inv_n;
    float a = alpha[c];
    float var = ex2 - m * m * (2.0f * a - a * a);
    float rs = rsqrtf(var + GN_EPS);
    float g = gamma[c] * rs;
    sAB[c] = g;
    sAB[UNITS + c] = beta[c] - g * a * m;
}

// ---------------- normalize + SiLU (in place, float4) ----------------

__global__ void k_norm_silu(float4* __restrict__ h, const float* __restrict__ sAB, int total4) {
    int gid = blockIdx.x * blockDim.x + threadIdx.x;
    if (gid >= total4) return;
    int c = (gid & 15) << 2;
    float4 v = h[gid];
    float a0 = sAB[c + 0], a1 = sAB[c + 1], a2 = sAB[c + 2], a3 = sAB[c + 3];
    float b0 = sAB[UNITS + c + 0], b1 = sAB[UNITS + c + 1], b2 = sAB[UNITS + c + 2], b3 = sAB[UNITS + c + 3];
    float t0 = fmaf(v.x, a0, b0);
    float t1 = fmaf(v.y, a1, b1);
    float t2 = fmaf(v.z, a2, b2);
    float t3 = fmaf(v.w, a3, b3);
    v.x = t0 / (1.0f + expf(-t0));
    v.y = t1 / (1.0f + expf(-t1));
    v.z = t2 / (1.0f + expf(-t2));
    v.w = t3 / (1.0f + expf(-t3));
    h[gid] = v;
}

// ---------------- final head ----------------

__global__ void k_head(const float* __restrict__ in, const float* __restrict__ wl,
                       const float* __restrict__ bl, float* __restrict__ out, int n) {
    int lane = threadIdx.x & 63;
    int wib = threadIdx.x >> 6;
    int wpb = blockDim.x >> 6;
    int gwave = blockIdx.x * wpb + wib;
    int nwaves = gridDim.x * wpb;
    float wv = wl[lane];
    float blv = bl[0];
    for (int node = gwave; node < n; node += nwaves) {
        float p = in[(size_t)node * UNITS + lane] * wv;
#pragma unroll
        for (int off = 32; off > 0; off >>= 1) p += __shfl_xor(p, off, 64);
        if (lane == 0) out[node] = 1.0f / (1.0f + expf(-(p + blv)));
    }
}

// ---------------- host launch ----------------

extern "C" void kernel_launch(void* const* d_in, const int* in_sizes, int n_in,
                              void* d_out, int out_size, void* d_ws, size_t ws_size,
                              hipStream_t stream) {
    const float* x = (const float*)d_in[0];
    const int* ei = (const int*)d_in[1];
    const float* conv_w0 = (const float*)d_in[2];
    const float* conv_w = (const float*)d_in[3];
    const float* conv_b = (const float*)d_in[4];
    const float* gn_gamma = (const float*)d_in[5];
    const float* gn_beta = (const float*)d_in[6];
    const float* gn_alpha = (const float*)d_in[7];
    const float* phe_w = (const float*)d_in[8];
    const float* phe_b = (const float*)d_in[9];
    const float* phe_wl = (const float*)d_in[10];
    const float* phe_bl = (const float*)d_in[11];
    const float* heu_w = (const float*)d_in[12];
    const float* heu_b = (const float*)d_in[13];
    const float* heu_wl = (const float*)d_in[14];
    const float* heu_bl = (const float*)d_in[15];

    const int N = in_sizes[0];
    const int E = in_sizes[1] / 2;
    const int NC = N * UNITS;

    const int* src = ei;
    const int* dstp = ei + E;

    char* w = (char*)d_ws;
    float* dinv = (float*)w;  w += (size_t)N * 4;
    float* nes = (float*)w;   w += (size_t)E * 4;
    float* h = (float*)w;     w += (size_t)NC * 4;
    float* h2 = (float*)w;    w += (size_t)NC * 4;
    float* h3 = (float*)w;    w += (size_t)NC * 4;
    float* stats = (float*)w; w += 128 * 4;
    float* sAB = (float*)w;   w += 128 * 4;
    int* cnt = (int*)w;       w += (size_t)N * 4;
    int* rowptr = (int*)w;    w += (size_t)(N + 1) * 4;
    int* fillc = (int*)w;     w += (size_t)N * 4;
    int* srcs = (int*)w;      w += (size_t)E * 4;

    float* out = (float*)d_out;

    const int B = 256;
    const int gE = (E + B - 1) / B;
    const int gN = (N + B - 1) / B;
    const int gNC = (NC + B - 1) / B;
    const int gNC4 = (NC / 4 + B - 1) / B;

    // ---- CSR build (per call; no cross-call state allowed) ----
    hipMemsetAsync(cnt, 0, (size_t)N * 4, stream);
    hipMemsetAsync(fillc, 0, (size_t)N * 4, stream);
    k_deg<<<gE, B, 0, stream>>>(dstp, cnt, E);
    k_dinv<<<gN, B, 0, stream>>>(cnt, dinv, N);
    k_scan<<<1, 1024, 0, stream>>>(cnt, rowptr, N);
    k_fill<<<gE, B, 0, stream>>>(src, dstp, dinv, rowptr, fillc, srcs, nes, E);

    // ---- GCN embedding layers ----
    for (int i = 0; i < DEPTH_EMB; ++i) {
        if (i == 0) {
            k_l0<<<gNC, B, 0, stream>>>(x, conv_w0, h2, N);
        } else {
            k_linear<0><<<2048, B, 0, stream>>>(h, h2, conv_w + (size_t)(i - 1) * UNITS * UNITS,
                                                nullptr, N);
        }
        int do_stats = (i < DEPTH_EMB - 1) ? 1 : 0;
        if (do_stats) {
            hipMemsetAsync(stats, 0, 128 * 4, stream);
            k_gather<1><<<2048, B, 0, stream>>>(h2, h, rowptr, srcs, nes, dinv,
                                                conv_b + (size_t)i * UNITS, stats, N);
            k_stats_final<<<1, 64, 0, stream>>>(stats, gn_gamma + (size_t)i * UNITS,
                                                gn_beta + (size_t)i * UNITS,
                                                gn_alpha + (size_t)i * UNITS, sAB, 1.0f / (float)N);
            k_norm_silu<<<gNC4, B, 0, stream>>>((float4*)h, sAB, NC / 4);
        } else {
            k_gather<0><<<2048, B, 0, stream>>>(h2, h, rowptr, srcs, nes, dinv,
                                                conv_b + (size_t)i * UNITS, stats, N);
        }
    }

    // ---- ParNet heads ----
    for (int head = 0; head < 2; ++head) {
        const float* wsrc = head == 0 ? phe_w : heu_w;
        const float* bsrc = head == 0 ? phe_b : heu_b;
        const float* wl = head == 0 ? phe_wl : heu_wl;
        const float* bl = head == 0 ? phe_bl : heu_bl;
        float* o = out + (size_t)head * N;

        const float* cur = h;
        float* nxt = h2;
        for (int l = 0; l < DEPTH_PAR - 1; ++l) {
            k_linear<1><<<2048, B, 0, stream>>>(cur, nxt, wsrc + (size_t)l * UNITS * UNITS,
                                                bsrc + (size_t)l * UNITS, N);
            cur = nxt;
            nxt = (nxt == h2) ? h3 : h2;
        }
        k_head<<<2048, B, 0, stream>>>(cur, wl, bl, o, N);
    }
}

// Round 3
// 1890.773 us; speedup vs baseline: 3.2423x; 1.1425x over previous
//
#include <hip/hip_runtime.h>
#include <hip/hip_bf16.h>
#include <math.h>

#define UNITS 64
#define DEPTH_EMB 12
#define DEPTH_PAR 5
#define GN_EPS 1e-5f

// ---------------- CSR build ----------------

__global__ void k_deg(const int* __restrict__ dst, int* __restrict__ cnt, int E) {
    int e = blockIdx.x * blockDim.x + threadIdx.x;
    if (e < E) atomicAdd(&cnt[dst[e]], 1);
}

__global__ void k_dinv(const int* __restrict__ cnt, float* __restrict__ dinv, int n) {
    int i = blockIdx.x * blockDim.x + threadIdx.x;
    if (i < n) dinv[i] = rsqrtf(1.0f + (float)cnt[i]);
}

// ---- parallel scan: chunk sums -> scan chunk sums -> local scan + offset ----
// chunk = 1024 elements

__global__ void k_chunksum(const int* __restrict__ cnt, int* __restrict__ csum, int n) {
    __shared__ int sd[256];
    int base = blockIdx.x * 1024;
    int s = 0;
    for (int i = threadIdx.x; i < 1024; i += 256) {
        int idx = base + i;
        if (idx < n) s += cnt[idx];
    }
    sd[threadIdx.x] = s;
    __syncthreads();
    for (int off = 128; off > 0; off >>= 1) {
        if (threadIdx.x < off) sd[threadIdx.x] += sd[threadIdx.x + off];
        __syncthreads();
    }
    if (threadIdx.x == 0) csum[blockIdx.x] = sd[0];
}

// exclusive scan of up to 256 chunk sums, single block of 256
__global__ void k_scansum(const int* __restrict__ csum, int* __restrict__ coff,
                          int* __restrict__ rowptr, int nchunks) {
    __shared__ int sd[256];
    int tid = threadIdx.x;
    int v = (tid < nchunks) ? csum[tid] : 0;
    sd[tid] = v;
    __syncthreads();
    for (int off = 1; off < 256; off <<= 1) {
        int t = (tid >= off) ? sd[tid - off] : 0;
        __syncthreads();
        sd[tid] += t;
        __syncthreads();
    }
    if (tid < nchunks) coff[tid] = sd[tid] - v;
    if (tid == 0) rowptr[0] = 0;
}

__global__ void k_scanfinal(const int* __restrict__ cnt, const int* __restrict__ coff,
                            int* __restrict__ rowptr, int n) {
    __shared__ int sd[1024];
    int base = blockIdx.x * 1024;
    int tid = threadIdx.x;
    int idx = base + tid;
    int v = (idx < n) ? cnt[idx] : 0;
    sd[tid] = v;
    __syncthreads();
    for (int off = 1; off < 1024; off <<= 1) {
        int t = (tid >= off) ? sd[tid - off] : 0;
        __syncthreads();
        sd[tid] += t;
        __syncthreads();
    }
    if (idx < n) rowptr[idx + 1] = coff[blockIdx.x] + sd[tid];
}

__global__ void k_fill(const int* __restrict__ src, const int* __restrict__ dst,
                       const float* __restrict__ dinv, const int* __restrict__ rowptr,
                       int* __restrict__ fill, int* __restrict__ srcs,
                       float* __restrict__ nes, int E) {
    int e = blockIdx.x * blockDim.x + threadIdx.x;
    if (e >= E) return;
    int s = src[e], d = dst[e];
    int p = rowptr[d] + atomicAdd(&fill[d], 1);
    srcs[p] = s;
    nes[p] = dinv[s] * dinv[d];
}

// ---------------- layer 0: h2 = x @ w0 ----------------

__global__ void k_l0(const float* __restrict__ x, const float* __restrict__ w0,
                     float* __restrict__ h2, int n) {
    int gid = blockIdx.x * blockDim.x + threadIdx.x;
    if (gid >= n * UNITS) return;
    int node = gid >> 6, c = gid & 63;
    h2[gid] = x[node] * w0[c];
}

// ---------------- 64x64 linear, scalar-broadcast row ----------------
// MODE 0: out = in @ W
// MODE 1: out = relu(in + in @ W + b)
template <int MODE>
__global__ void k_linear(const float* __restrict__ in, float* __restrict__ out,
                         const float* __restrict__ W, const float* __restrict__ b, int n) {
    int lane = threadIdx.x & 63;
    int wib = threadIdx.x >> 6;
    int wpb = blockDim.x >> 6;
    int gwave = blockIdx.x * wpb + wib;
    int nwaves = gridDim.x * wpb;

    float w[UNITS];
#pragma unroll
    for (int k = 0; k < UNITS; ++k) w[k] = W[k * UNITS + lane];
    float bj = (MODE == 1) ? b[lane] : 0.0f;

    for (int nd = gwave; nd < n; nd += nwaves) {
        int node = __builtin_amdgcn_readfirstlane(nd);
        const float* __restrict__ row = in + (size_t)node * UNITS;
        float a0 = 0.0f, a1 = 0.0f, a2 = 0.0f, a3 = 0.0f;
#pragma unroll
        for (int k = 0; k < UNITS; k += 4) {
            a0 = fmaf(row[k + 0], w[k + 0], a0);
            a1 = fmaf(row[k + 1], w[k + 1], a1);
            a2 = fmaf(row[k + 2], w[k + 2], a2);
            a3 = fmaf(row[k + 3], w[k + 3], a3);
        }
        float acc = (a0 + a1) + (a2 + a3);
        if (MODE == 1) {
            acc += row[lane] + bj;
            acc = fmaxf(acc, 0.0f);
        }
        out[(size_t)node * UNITS + lane] = acc;
    }
}

// ---------------- gather + combine + stats ----------------

template <int DO_STATS>
__global__ void k_gather(const float* __restrict__ h2, float* __restrict__ h,
                         const int* __restrict__ rowptr, const int* __restrict__ srcs,
                         const float* __restrict__ nes, const float* __restrict__ dinv,
                         const float* __restrict__ b, float* __restrict__ stats, int n) {
    int lane = threadIdx.x & 63;
    int wib = threadIdx.x >> 6;
    int wpb = blockDim.x >> 6;
    int gwave = blockIdx.x * wpb + wib;
    int nwaves = gridDim.x * wpb;
    float bj = b[lane];
    float s1 = 0.0f, s2 = 0.0f;

    for (int nd = gwave; nd < n; nd += nwaves) {
        int node = __builtin_amdgcn_readfirstlane(nd);
        int beg = rowptr[node], end = rowptr[node + 1];
        float di = dinv[node];
        float acc0 = fmaf(h2[(size_t)node * UNITS + lane], di * di, bj);
        float acc1 = 0.0f, acc2 = 0.0f, acc3 = 0.0f;
        int j = beg;
        for (; j + 8 <= end; j += 8) {
            int i0 = srcs[j + 0], i1 = srcs[j + 1], i2 = srcs[j + 2], i3 = srcs[j + 3];
            int i4 = srcs[j + 4], i5 = srcs[j + 5], i6 = srcs[j + 6], i7 = srcs[j + 7];
            float w0 = nes[j + 0], w1 = nes[j + 1], w2 = nes[j + 2], w3 = nes[j + 3];
            float w4 = nes[j + 4], w5 = nes[j + 5], w6 = nes[j + 6], w7 = nes[j + 7];
            float v0 = h2[(size_t)i0 * UNITS + lane];
            float v1 = h2[(size_t)i1 * UNITS + lane];
            float v2 = h2[(size_t)i2 * UNITS + lane];
            float v3 = h2[(size_t)i3 * UNITS + lane];
            float v4 = h2[(size_t)i4 * UNITS + lane];
            float v5 = h2[(size_t)i5 * UNITS + lane];
            float v6 = h2[(size_t)i6 * UNITS + lane];
            float v7 = h2[(size_t)i7 * UNITS + lane];
            acc0 = fmaf(w0, v0, acc0);
            acc1 = fmaf(w1, v1, acc1);
            acc2 = fmaf(w2, v2, acc2);
            acc3 = fmaf(w3, v3, acc3);
            acc0 = fmaf(w4, v4, acc0);
            acc1 = fmaf(w5, v5, acc1);
            acc2 = fmaf(w6, v6, acc2);
            acc3 = fmaf(w7, v7, acc3);
        }
        for (; j + 4 <= end; j += 4) {
            int i0 = srcs[j + 0], i1 = srcs[j + 1], i2 = srcs[j + 2], i3 = srcs[j + 3];
            float w0 = nes[j + 0], w1 = nes[j + 1], w2 = nes[j + 2], w3 = nes[j + 3];
            float v0 = h2[(size_t)i0 * UNITS + lane];
            float v1 = h2[(size_t)i1 * UNITS + lane];
            float v2 = h2[(size_t)i2 * UNITS + lane];
            float v3 = h2[(size_t)i3 * UNITS + lane];
            acc0 = fmaf(w0, v0, acc0);
            acc1 = fmaf(w1, v1, acc1);
            acc2 = fmaf(w2, v2, acc2);
            acc3 = fmaf(w3, v3, acc3);
        }
        for (; j < end; ++j) acc0 = fmaf(nes[j], h2[(size_t)srcs[j] * UNITS + lane], acc0);
        float acc = (acc0 + acc1) + (acc2 + acc3);
        h[(size_t)node * UNITS + lane] = acc;
        if (DO_STATS) {
            s1 += acc;
            s2 = fmaf(acc, acc, s2);
        }
    }

    if (DO_STATS) {
        __shared__ float sd[2][4][UNITS];
        sd[0][wib][lane] = s1;
        sd[1][wib][lane] = s2;
        __syncthreads();
        if (threadIdx.x < UNITS) {
            float a1 = 0.0f, a2 = 0.0f;
            for (int r = 0; r < wpb; ++r) {
                a1 += sd[0][r][lane];
                a2 += sd[1][r][lane];
            }
            atomicAdd(&stats[lane], a1);
            atomicAdd(&stats[UNITS + lane], a2);
        }
    }
}

// ---------------- normalize + SiLU (stats finalize fused, float4, grid-stride) ----------------

__global__ void k_norm_silu(float4* __restrict__ h, const float* __restrict__ stats,
                            const float* __restrict__ gamma, const float* __restrict__ beta,
                            const float* __restrict__ alpha, float inv_n, int total4) {
    int tid = blockIdx.x * blockDim.x + threadIdx.x;
    int c = (tid & 15) << 2;
    float A[4], Bc[4];
#pragma unroll
    for (int q = 0; q < 4; ++q) {
        float m = stats[c + q] * inv_n;
        float ex2 = stats[UNITS + c + q] * inv_n;
        float a = alpha[c + q];
        float var = ex2 - m * m * (2.0f * a - a * a);
        float g = gamma[c + q] * rsqrtf(var + GN_EPS);
        A[q] = g;
        Bc[q] = beta[c + q] - g * a * m;
    }
    int stride = gridDim.x * blockDim.x;
    for (int gid = tid; gid < total4; gid += stride) {
        float4 v = h[gid];
        float t0 = fmaf(v.x, A[0], Bc[0]);
        float t1 = fmaf(v.y, A[1], Bc[1]);
        float t2 = fmaf(v.z, A[2], Bc[2]);
        float t3 = fmaf(v.w, A[3], Bc[3]);
        v.x = t0 / (1.0f + expf(-t0));
        v.y = t1 / (1.0f + expf(-t1));
        v.z = t2 / (1.0f + expf(-t2));
        v.w = t3 / (1.0f + expf(-t3));
        h[gid] = v;
    }
}

// ---------------- final head ----------------

__global__ void k_head(const float* __restrict__ in, const float* __restrict__ wl,
                       const float* __restrict__ bl, float* __restrict__ out, int n) {
    int lane = threadIdx.x & 63;
    int wib = threadIdx.x >> 6;
    int wpb = blockDim.x >> 6;
    int gwave = blockIdx.x * wpb + wib;
    int nwaves = gridDim.x * wpb;
    float wv = wl[lane];
    float blv = bl[0];
    for (int node = gwave; node < n; node += nwaves) {
        float p = in[(size_t)node * UNITS + lane] * wv;
#pragma unroll
        for (int off = 32; off > 0; off >>= 1) p += __shfl_xor(p, off, 64);
        if (lane == 0) out[node] = 1.0f / (1.0f + expf(-(p + blv)));
    }
}

// ---------------- host launch ----------------

extern "C" void kernel_launch(void* const* d_in, const int* in_sizes, int n_in,
                              void* d_out, int out_size, void* d_ws, size_t ws_size,
                              hipStream_t stream) {
    const float* x = (const float*)d_in[0];
    const int* ei = (const int*)d_in[1];
    const float* conv_w0 = (const float*)d_in[2];
    const float* conv_w = (const float*)d_in[3];
    const float* conv_b = (const float*)d_in[4];
    const float* gn_gamma = (const float*)d_in[5];
    const float* gn_beta = (const float*)d_in[6];
    const float* gn_alpha = (const float*)d_in[7];
    const float* phe_w = (const float*)d_in[8];
    const float* phe_b = (const float*)d_in[9];
    const float* phe_wl = (const float*)d_in[10];
    const float* phe_bl = (const float*)d_in[11];
    const float* heu_w = (const float*)d_in[12];
    const float* heu_b = (const float*)d_in[13];
    const float* heu_wl = (const float*)d_in[14];
    const float* heu_bl = (const float*)d_in[15];

    const int N = in_sizes[0];
    const int E = in_sizes[1] / 2;
    const int NC = N * UNITS;
    const int NCHUNK = (N + 1023) / 1024;

    const int* src = ei;
    const int* dstp = ei + E;

    char* w = (char*)d_ws;
    float* dinv = (float*)w;  w += (size_t)N * 4;
    float* nes = (float*)w;   w += (size_t)E * 4;
    float* h = (float*)w;     w += (size_t)NC * 4;
    float* h2 = (float*)w;    w += (size_t)NC * 4;
    float* h3 = (float*)w;    w += (size_t)NC * 4;
    float* stats = (float*)w; w += 128 * 4;
    int* cnt = (int*)w;       w += (size_t)N * 4;
    int* rowptr = (int*)w;    w += (size_t)(N + 1) * 4;
    int* fillc = (int*)w;     w += (size_t)N * 4;
    int* srcs = (int*)w;      w += (size_t)E * 4;
    int* csum = (int*)w;      w += 256 * 4;
    int* coff = (int*)w;      w += 256 * 4;

    float* out = (float*)d_out;

    const int B = 256;
    const int gE = (E + B - 1) / B;
    const int gN = (N + B - 1) / B;
    const int gNC = (NC + B - 1) / B;

    // ---- CSR build ----
    hipMemsetAsync(cnt, 0, (size_t)N * 4, stream);
    hipMemsetAsync(fillc, 0, (size_t)N * 4, stream);
    k_deg<<<gE, B, 0, stream>>>(dstp, cnt, E);
    k_dinv<<<gN, B, 0, stream>>>(cnt, dinv, N);
    k_chunksum<<<NCHUNK, 256, 0, stream>>>(cnt, csum, N);
    k_scansum<<<1, 256, 0, stream>>>(csum, coff, rowptr, NCHUNK);
    k_scanfinal<<<NCHUNK, 1024, 0, stream>>>(cnt, coff, rowptr, N);
    k_fill<<<gE, B, 0, stream>>>(src, dstp, dinv, rowptr, fillc, srcs, nes, E);

    // ---- GCN embedding layers ----
    for (int i = 0; i < DEPTH_EMB; ++i) {
        if (i == 0) {
            k_l0<<<gNC, B, 0, stream>>>(x, conv_w0, h2, N);
        } else {
            k_linear<0><<<2048, B, 0, stream>>>(h, h2, conv_w + (size_t)(i - 1) * UNITS * UNITS,
                                                nullptr, N);
        }
        int do_stats = (i < DEPTH_EMB - 1) ? 1 : 0;
        if (do_stats) {
            hipMemsetAsync(stats, 0, 128 * 4, stream);
            k_gather<1><<<2048, B, 0, stream>>>(h2, h, rowptr, srcs, nes, dinv,
                                                conv_b + (size_t)i * UNITS, stats, N);
            k_norm_silu<<<2048, B, 0, stream>>>((float4*)h, stats,
                                                gn_gamma + (size_t)i * UNITS,
                                                gn_beta + (size_t)i * UNITS,
                                                gn_alpha + (size_t)i * UNITS,
                                                1.0f / (float)N, NC / 4);
        } else {
            k_gather<0><<<2048, B, 0, stream>>>(h2, h, rowptr, srcs, nes, dinv,
                                                conv_b + (size_t)i * UNITS, stats, N);
        }
    }

    // ---- ParNet heads ----
    for (int head = 0; head < 2; ++head) {
        const float* wsrc = head == 0 ? phe_w : heu_w;
        const float* bsrc = head == 0 ? phe_b : heu_b;
        const float* wl = head == 0 ? phe_wl : heu_wl;
        const float* bl = head == 0 ? phe_bl : heu_bl;
        float* o = out + (size_t)head * N;

        const float* cur = h;
        float* nxt = h2;
        for (int l = 0; l < DEPTH_PAR - 1; ++l) {
            k_linear<1><<<2048, B, 0, stream>>>(cur, nxt, wsrc + (size_t)l * UNITS * UNITS,
                                                bsrc + (size_t)l * UNITS, N);
            cur = nxt;
            nxt = (nxt == h2) ? h3 : h2;
        }
        k_head<<<2048, B, 0, stream>>>(cur, wl, bl, o, N);
    }
}

// Round 4
// 1707.329 us; speedup vs baseline: 3.5906x; 1.1074x over previous
//
#include <hip/hip_runtime.h>
#include <hip/hip_bf16.h>
#include <hip/hip_fp16.h>
#include <math.h>

#define UNITS 64
#define DEPTH_EMB 12
#define DEPTH_PAR 5
#define GN_EPS 1e-5f

// ---------------- CSR build ----------------

__global__ void k_deg(const int* __restrict__ dst, int* __restrict__ cnt, int E) {
    int e = blockIdx.x * blockDim.x + threadIdx.x;
    if (e < E) atomicAdd(&cnt[dst[e]], 1);
}

__global__ void k_dinv(const int* __restrict__ cnt, float* __restrict__ dinv, int n) {
    int i = blockIdx.x * blockDim.x + threadIdx.x;
    if (i < n) dinv[i] = rsqrtf(1.0f + (float)cnt[i]);
}

// ---- parallel scan: chunk sums -> scan chunk sums -> local scan + offset ----

__global__ void k_chunksum(const int* __restrict__ cnt, int* __restrict__ csum, int n) {
    __shared__ int sd[256];
    int base = blockIdx.x * 1024;
    int s = 0;
    for (int i = threadIdx.x; i < 1024; i += 256) {
        int idx = base + i;
        if (idx < n) s += cnt[idx];
    }
    sd[threadIdx.x] = s;
    __syncthreads();
    for (int off = 128; off > 0; off >>= 1) {
        if (threadIdx.x < off) sd[threadIdx.x] += sd[threadIdx.x + off];
        __syncthreads();
    }
    if (threadIdx.x == 0) csum[blockIdx.x] = sd[0];
}

__global__ void k_scansum(const int* __restrict__ csum, int* __restrict__ coff,
                          int* __restrict__ rowptr, int nchunks) {
    __shared__ int sd[256];
    int tid = threadIdx.x;
    int v = (tid < nchunks) ? csum[tid] : 0;
    sd[tid] = v;
    __syncthreads();
    for (int off = 1; off < 256; off <<= 1) {
        int t = (tid >= off) ? sd[tid - off] : 0;
        __syncthreads();
        sd[tid] += t;
        __syncthreads();
    }
    if (tid < nchunks) coff[tid] = sd[tid] - v;
    if (tid == 0) rowptr[0] = 0;
}

__global__ void k_scanfinal(const int* __restrict__ cnt, const int* __restrict__ coff,
                            int* __restrict__ rowptr, int n) {
    __shared__ int sd[1024];
    int base = blockIdx.x * 1024;
    int tid = threadIdx.x;
    int idx = base + tid;
    int v = (idx < n) ? cnt[idx] : 0;
    sd[tid] = v;
    __syncthreads();
    for (int off = 1; off < 1024; off <<= 1) {
        int t = (tid >= off) ? sd[tid - off] : 0;
        __syncthreads();
        sd[tid] += t;
        __syncthreads();
    }
    if (idx < n) rowptr[idx + 1] = coff[blockIdx.x] + sd[tid];
}

// fill: only src indices now (edge weight factorized away)
__global__ void k_fill(const int* __restrict__ src, const int* __restrict__ dst,
                       const int* __restrict__ rowptr, int* __restrict__ fill,
                       int* __restrict__ srcs, int E) {
    int e = blockIdx.x * blockDim.x + threadIdx.x;
    if (e >= E) return;
    int s = src[e], d = dst[e];
    int p = rowptr[d] + atomicAdd(&fill[d], 1);
    srcs[p] = s;
}

// ---------------- layer 0: h2 = f16(dinv * (x @ w0)) ----------------

__global__ void k_l0(const float* __restrict__ x, const float* __restrict__ w0,
                     const float* __restrict__ dinv, __half* __restrict__ h2, int n) {
    int gid = blockIdx.x * blockDim.x + threadIdx.x;
    if (gid >= n * UNITS) return;
    int node = gid >> 6, c = gid & 63;
    h2[gid] = __float2half(x[node] * w0[c] * dinv[node]);
}

// ---------------- 64x64 linear, scalar-broadcast row ----------------
// embedding variant: out_h = f16(dinv[node] * (in @ W))
__global__ void k_linear_emb(const float* __restrict__ in, __half* __restrict__ out,
                             const float* __restrict__ W, const float* __restrict__ dinv, int n) {
    int lane = threadIdx.x & 63;
    int wib = threadIdx.x >> 6;
    int wpb = blockDim.x >> 6;
    int gwave = blockIdx.x * wpb + wib;
    int nwaves = gridDim.x * wpb;

    float w[UNITS];
#pragma unroll
    for (int k = 0; k < UNITS; ++k) w[k] = W[k * UNITS + lane];

    for (int nd = gwave; nd < n; nd += nwaves) {
        int node = __builtin_amdgcn_readfirstlane(nd);
        const float* __restrict__ row = in + (size_t)node * UNITS;
        float di = dinv[node];
        float a0 = 0.0f, a1 = 0.0f, a2 = 0.0f, a3 = 0.0f;
#pragma unroll
        for (int k = 0; k < UNITS; k += 4) {
            a0 = fmaf(row[k + 0], w[k + 0], a0);
            a1 = fmaf(row[k + 1], w[k + 1], a1);
            a2 = fmaf(row[k + 2], w[k + 2], a2);
            a3 = fmaf(row[k + 3], w[k + 3], a3);
        }
        float acc = (a0 + a1) + (a2 + a3);
        out[(size_t)node * UNITS + lane] = __float2half(acc * di);
    }
}

// parnet variant: out = relu(in + in @ W + b), fp32
__global__ void k_linear_par(const float* __restrict__ in, float* __restrict__ out,
                             const float* __restrict__ W, const float* __restrict__ b, int n) {
    int lane = threadIdx.x & 63;
    int wib = threadIdx.x >> 6;
    int wpb = blockDim.x >> 6;
    int gwave = blockIdx.x * wpb + wib;
    int nwaves = gridDim.x * wpb;

    float w[UNITS];
#pragma unroll
    for (int k = 0; k < UNITS; ++k) w[k] = W[k * UNITS + lane];
    float bj = b[lane];

    for (int nd = gwave; nd < n; nd += nwaves) {
        int node = __builtin_amdgcn_readfirstlane(nd);
        const float* __restrict__ row = in + (size_t)node * UNITS;
        float a0 = 0.0f, a1 = 0.0f, a2 = 0.0f, a3 = 0.0f;
#pragma unroll
        for (int k = 0; k < UNITS; k += 4) {
            a0 = fmaf(row[k + 0], w[k + 0], a0);
            a1 = fmaf(row[k + 1], w[k + 1], a1);
            a2 = fmaf(row[k + 2], w[k + 2], a2);
            a3 = fmaf(row[k + 3], w[k + 3], a3);
        }
        float acc = (a0 + a1) + (a2 + a3) + row[lane] + bj;
        acc = fmaxf(acc, 0.0f);
        out[(size_t)node * UNITS + lane] = acc;
    }
}

// ---------------- gather: h[d] = dinv[d]*(sum srcs rows + own row) + b ----------------

template <int DO_STATS>
__global__ void k_gather(const __half* __restrict__ h2, float* __restrict__ h,
                         const int* __restrict__ rowptr, const int* __restrict__ srcs,
                         const float* __restrict__ dinv, const float* __restrict__ b,
                         float* __restrict__ stats, int n) {
    int lane = threadIdx.x & 63;
    int wib = threadIdx.x >> 6;
    int wpb = blockDim.x >> 6;
    int gwave = blockIdx.x * wpb + wib;
    int nwaves = gridDim.x * wpb;
    float bj = b[lane];
    float s1 = 0.0f, s2 = 0.0f;

    for (int nd = gwave; nd < n; nd += nwaves) {
        int node = __builtin_amdgcn_readfirstlane(nd);
        int beg = rowptr[node], end = rowptr[node + 1];
        float di = dinv[node];
        float acc0 = __half2float(h2[(size_t)node * UNITS + lane]);   // self row
        float acc1 = 0.0f, acc2 = 0.0f, acc3 = 0.0f;
        int j = beg;
        for (; j + 8 <= end; j += 8) {
            int i0 = srcs[j + 0], i1 = srcs[j + 1], i2 = srcs[j + 2], i3 = srcs[j + 3];
            int i4 = srcs[j + 4], i5 = srcs[j + 5], i6 = srcs[j + 6], i7 = srcs[j + 7];
            float v0 = __half2float(h2[(size_t)i0 * UNITS + lane]);
            float v1 = __half2float(h2[(size_t)i1 * UNITS + lane]);
            float v2 = __half2float(h2[(size_t)i2 * UNITS + lane]);
            float v3 = __half2float(h2[(size_t)i3 * UNITS + lane]);
            float v4 = __half2float(h2[(size_t)i4 * UNITS + lane]);
            float v5 = __half2float(h2[(size_t)i5 * UNITS + lane]);
            float v6 = __half2float(h2[(size_t)i6 * UNITS + lane]);
            float v7 = __half2float(h2[(size_t)i7 * UNITS + lane]);
            acc0 += v0; acc1 += v1; acc2 += v2; acc3 += v3;
            acc0 += v4; acc1 += v5; acc2 += v6; acc3 += v7;
        }
        for (; j + 4 <= end; j += 4) {
            int i0 = srcs[j + 0], i1 = srcs[j + 1], i2 = srcs[j + 2], i3 = srcs[j + 3];
            float v0 = __half2float(h2[(size_t)i0 * UNITS + lane]);
            float v1 = __half2float(h2[(size_t)i1 * UNITS + lane]);
            float v2 = __half2float(h2[(size_t)i2 * UNITS + lane]);
            float v3 = __half2float(h2[(size_t)i3 * UNITS + lane]);
            acc0 += v0; acc1 += v1; acc2 += v2; acc3 += v3;
        }
        for (; j < end; ++j) acc0 += __half2float(h2[(size_t)srcs[j] * UNITS + lane]);
        float acc = (acc0 + acc1) + (acc2 + acc3);
        float hv = fmaf(acc, di, bj);
        h[(size_t)node * UNITS + lane] = hv;
        if (DO_STATS) {
            s1 += hv;
            s2 = fmaf(hv, hv, s2);
        }
    }

    if (DO_STATS) {
        __shared__ float sd[2][4][UNITS];
        sd[0][wib][lane] = s1;
        sd[1][wib][lane] = s2;
        __syncthreads();
        if (threadIdx.x < UNITS) {
            float a1 = 0.0f, a2 = 0.0f;
            for (int r = 0; r < wpb; ++r) {
                a1 += sd[0][r][lane];
                a2 += sd[1][r][lane];
            }
            atomicAdd(&stats[lane], a1);
            atomicAdd(&stats[UNITS + lane], a2);
        }
    }
}

// ---------------- normalize + SiLU (stats finalize fused, float4, grid-stride) ----------------

__global__ void k_norm_silu(float4* __restrict__ h, const float* __restrict__ stats,
                            const float* __restrict__ gamma, const float* __restrict__ beta,
                            const float* __restrict__ alpha, float inv_n, int total4) {
    int tid = blockIdx.x * blockDim.x + threadIdx.x;
    int c = (tid & 15) << 2;
    float A[4], Bc[4];
#pragma unroll
    for (int q = 0; q < 4; ++q) {
        float m = stats[c + q] * inv_n;
        float ex2 = stats[UNITS + c + q] * inv_n;
        float a = alpha[c + q];
        float var = ex2 - m * m * (2.0f * a - a * a);
        float g = gamma[c + q] * rsqrtf(var + GN_EPS);
        A[q] = g;
        Bc[q] = beta[c + q] - g * a * m;
    }
    int stride = gridDim.x * blockDim.x;
    for (int gid = tid; gid < total4; gid += stride) {
        float4 v = h[gid];
        float t0 = fmaf(v.x, A[0], Bc[0]);
        float t1 = fmaf(v.y, A[1], Bc[1]);
        float t2 = fmaf(v.z, A[2], Bc[2]);
        float t3 = fmaf(v.w, A[3], Bc[3]);
        v.x = t0 / (1.0f + __expf(-t0));
        v.y = t1 / (1.0f + __expf(-t1));
        v.z = t2 / (1.0f + __expf(-t2));
        v.w = t3 / (1.0f + __expf(-t3));
        h[gid] = v;
    }
}

// ---------------- final head ----------------

__global__ void k_head(const float* __restrict__ in, const float* __restrict__ wl,
                       const float* __restrict__ bl, float* __restrict__ out, int n) {
    int lane = threadIdx.x & 63;
    int wib = threadIdx.x >> 6;
    int wpb = blockDim.x >> 6;
    int gwave = blockIdx.x * wpb + wib;
    int nwaves = gridDim.x * wpb;
    float wv = wl[lane];
    float blv = bl[0];
    for (int node = gwave; node < n; node += nwaves) {
        float p = in[(size_t)node * UNITS + lane] * wv;
#pragma unroll
        for (int off = 32; off > 0; off >>= 1) p += __shfl_xor(p, off, 64);
        if (lane == 0) out[node] = 1.0f / (1.0f + __expf(-(p + blv)));
    }
}

// ---------------- host launch ----------------

extern "C" void kernel_launch(void* const* d_in, const int* in_sizes, int n_in,
                              void* d_out, int out_size, void* d_ws, size_t ws_size,
                              hipStream_t stream) {
    const float* x = (const float*)d_in[0];
    const int* ei = (const int*)d_in[1];
    const float* conv_w0 = (const float*)d_in[2];
    const float* conv_w = (const float*)d_in[3];
    const float* conv_b = (const float*)d_in[4];
    const float* gn_gamma = (const float*)d_in[5];
    const float* gn_beta = (const float*)d_in[6];
    const float* gn_alpha = (const float*)d_in[7];
    const float* phe_w = (const float*)d_in[8];
    const float* phe_b = (const float*)d_in[9];
    const float* phe_wl = (const float*)d_in[10];
    const float* phe_bl = (const float*)d_in[11];
    const float* heu_w = (const float*)d_in[12];
    const float* heu_b = (const float*)d_in[13];
    const float* heu_wl = (const float*)d_in[14];
    const float* heu_bl = (const float*)d_in[15];

    const int N = in_sizes[0];
    const int E = in_sizes[1] / 2;
    const int NC = N * UNITS;
    const int NCHUNK = (N + 1023) / 1024;

    const int* src = ei;
    const int* dstp = ei + E;

    char* w = (char*)d_ws;
    float* dinv = (float*)w;  w += (size_t)N * 4;
    float* h = (float*)w;     w += (size_t)NC * 4;
    float* hx = (float*)w;    w += (size_t)NC * 4;   // f16 h2 during embedding; fp32 parnet buffer
    float* h3 = (float*)w;    w += (size_t)NC * 4;
    float* stats = (float*)w; w += 128 * 4;
    int* cnt = (int*)w;       w += (size_t)N * 4;
    int* rowptr = (int*)w;    w += (size_t)(N + 1) * 4;
    int* fillc = (int*)w;     w += (size_t)N * 4;
    int* srcs = (int*)w;      w += (size_t)E * 4;
    int* csum = (int*)w;      w += 256 * 4;
    int* coff = (int*)w;      w += 256 * 4;

    __half* h2 = (__half*)hx;
    float* out = (float*)d_out;

    const int B = 256;
    const int gE = (E + B - 1) / B;
    const int gN = (N + B - 1) / B;
    const int gNC = (NC + B - 1) / B;

    // ---- CSR build ----
    hipMemsetAsync(cnt, 0, (size_t)N * 4, stream);
    hipMemsetAsync(fillc, 0, (size_t)N * 4, stream);
    k_deg<<<gE, B, 0, stream>>>(dstp, cnt, E);
    k_dinv<<<gN, B, 0, stream>>>(cnt, dinv, N);
    k_chunksum<<<NCHUNK, 256, 0, stream>>>(cnt, csum, N);
    k_scansum<<<1, 256, 0, stream>>>(csum, coff, rowptr, NCHUNK);
    k_scanfinal<<<NCHUNK, 1024, 0, stream>>>(cnt, coff, rowptr, N);
    k_fill<<<gE, B, 0, stream>>>(src, dstp, rowptr, fillc, srcs, E);

    // ---- GCN embedding layers ----
    for (int i = 0; i < DEPTH_EMB; ++i) {
        if (i == 0) {
            k_l0<<<gNC, B, 0, stream>>>(x, conv_w0, dinv, h2, N);
        } else {
            k_linear_emb<<<2048, B, 0, stream>>>(h, h2, conv_w + (size_t)(i - 1) * UNITS * UNITS,
                                                 dinv, N);
        }
        int do_stats = (i < DEPTH_EMB - 1) ? 1 : 0;
        if (do_stats) {
            hipMemsetAsync(stats, 0, 128 * 4, stream);
            k_gather<1><<<2048, B, 0, stream>>>(h2, h, rowptr, srcs, dinv,
                                                conv_b + (size_t)i * UNITS, stats, N);
            k_norm_silu<<<2048, B, 0, stream>>>((float4*)h, stats,
                                                gn_gamma + (size_t)i * UNITS,
                                                gn_beta + (size_t)i * UNITS,
                                                gn_alpha + (size_t)i * UNITS,
                                                1.0f / (float)N, NC / 4);
        } else {
            k_gather<0><<<2048, B, 0, stream>>>(h2, h, rowptr, srcs, dinv,
                                                conv_b + (size_t)i * UNITS, stats, N);
        }
    }

    // ---- ParNet heads (h preserved; ping-pong h3 / hx) ----
    for (int head = 0; head < 2; ++head) {
        const float* wsrc = head == 0 ? phe_w : heu_w;
        const float* bsrc = head == 0 ? phe_b : heu_b;
        const float* wl = head == 0 ? phe_wl : heu_wl;
        const float* bl = head == 0 ? phe_bl : heu_bl;
        float* o = out + (size_t)head * N;

        const float* cur = h;
        float* nxt = h3;
        for (int l = 0; l < DEPTH_PAR - 1; ++l) {
            k_linear_par<<<2048, B, 0, stream>>>(cur, nxt, wsrc + (size_t)l * UNITS * UNITS,
                                                 bsrc + (size_t)l * UNITS, N);
            cur = nxt;
            nxt = (nxt == h3) ? hx : h3;
        }
        k_head<<<2048, B, 0, stream>>>(cur, wl, bl, o, N);
    }
}